// Round 1
// baseline (1020.310 us; speedup 1.0000x reference)
//
#include <hip/hip_runtime.h>

typedef unsigned short u16;
typedef unsigned int u32;
typedef unsigned long long u64;

#define B_TOTAL 65536
#define H 512
#define D 64
#define BM 64

typedef __bf16 bf16x8 __attribute__((ext_vector_type(8)));
typedef float f32x4 __attribute__((ext_vector_type(4)));

__device__ __forceinline__ u32 f2b(float f) {  // fp32 -> bf16 bits, RNE
  u32 u = __builtin_bit_cast(u32, f);
  return (u + 0x7fffu + ((u >> 16) & 1u)) >> 16;
}
__device__ __forceinline__ float b2f(u32 bits) {
  return __builtin_bit_cast(float, bits << 16);
}

// ---- workspace layout (bf16 element offsets) ----
// Weight regions are FRAGMENT-PACKED: for logical B-matrix M[NN][KK],
// packed[( (n>>4)*(KK/32) + (k>>5) )*512 + lane*8 + j] = M[n][k],
// n = ntile*16 + (lane&15), k = kstep*32 + (lane>>4)*8 + j.
#define OFF_Wz0b 0          /* [N=512][K=64]  fwd L0 */
#define OFF_Wx0b 32768
#define OFF_Wx1b 65536
#define OFF_Wx2b 98304
#define OFF_Wz1b 131072     /* [N=512][K=512] fwd */
#define OFF_Wz2b 393216
#define OFF_Wz3b 655360
#define OFF_Wz1t 917504     /* [N=512][K=512] transposed, bwd */
#define OFF_Wz2t 1179648
#define OFF_Wz3t 1441792
#define OFF_Wz0t 1703936    /* [N=64][K=512] transposed grad weights */
#define OFF_Wx0t 1736704
#define OFF_Wx1t 1769472
#define OFF_Wx2t 1802240
#define OFF_WEND 1835008
#define SLAB_ELEMS (B_TOTAL * H)          /* 33,554,432 bf16 per slab */
#define OFF_S0 OFF_WEND
#define OFF_S1 (OFF_S0 + SLAB_ELEMS)
#define OFF_S2 (OFF_S1 + SLAB_ELEMS)
#define WS_ELEMS (OFF_S2 + SLAB_ELEMS)    /* ~102.5M elems = ~205 MB */

// ---- weight prep: fp32 -> bf16, fragment-packed (+ transposed variants) ----
__global__ __launch_bounds__(256) void prep_kernel(
    const float* __restrict__ Wz0, const float* __restrict__ Wz1,
    const float* __restrict__ Wz2, const float* __restrict__ Wz3,
    const float* __restrict__ Wx0, const float* __restrict__ Wx1,
    const float* __restrict__ Wx2, u16* __restrict__ wsb) {
  int i = blockIdx.x * 256 + threadIdx.x;   // grid exactly covers OFF_WEND
  const float* src;
  int NN, KK, trans, p;
  if (i < 131072) {                          // x-path fwd: [512][64] direct
    int r = i >> 15; p = i & 32767;
    src = (r == 0) ? Wz0 : (r == 1) ? Wx0 : (r == 2) ? Wx1 : Wx2;
    NN = 512; KK = 64; trans = 0;
  } else if (i < 917504) {                   // H fwd: [512][512] direct
    int j = i - 131072; int r = j >> 18; p = j & 262143;
    src = (r == 0) ? Wz1 : (r == 1) ? Wz2 : Wz3;
    NN = 512; KK = 512; trans = 0;
  } else if (i < 1703936) {                  // H bwd: transposed
    int j = i - 917504; int r = j >> 18; p = j & 262143;
    src = (r == 0) ? Wz1 : (r == 1) ? Wz2 : Wz3;
    NN = 512; KK = 512; trans = 1;
  } else {                                   // grad weights: [64][512] = W^T
    int j = i - 1703936; int r = j >> 15; p = j & 32767;
    src = (r == 0) ? Wz0 : (r == 1) ? Wx0 : (r == 2) ? Wx1 : Wx2;
    NN = 64; KK = 512; trans = 1;
  }
  int jj = p & 7, lane = (p >> 3) & 63, blk = p >> 9;
  int kt_sh = (KK == 64) ? 1 : 4;            // log2(KK/32)
  int ntile = blk >> kt_sh;
  int kstep = blk & ((1 << kt_sh) - 1);
  int n = ntile * 16 + (lane & 15);
  int k = kstep * 32 + ((lane >> 4) << 3) + jj;
  float v = trans ? src[k * NN + n] : src[n * KK + k];
  wsb[i] = (u16)f2b(v);
}

__global__ __launch_bounds__(256) void fill_sentinel(float* out, int n) {
  int i = blockIdx.x * 256 + threadIdx.x;
  if (i < n) out[i] = 12345.0f;   // unmistakable "workspace too small" marker
}

// ---- fully-fused ICNN fwd+bwd (single GEMM kernel) ----
// 512 thr = 8 waves, BM=64 rows; wave w owns cols [w*64,+64) of the [64,512]
// GEMMs (acc[4][4] = 64 AGPR).
// OCCUPANCY REWORK vs previous version: LDS cut 144 KB -> 73 KB so TWO blocks
// co-reside per CU (was 1; OccupancyPercent 23% -> ~46%). The wbuf weight
// staging was per-wave PRIVATE (no cross-wave sharing), so weights now stream
// global->VGPR directly (unrolled loop; compiler pipelines the loads) — no LDS,
// no vmcnt coupling. The fp32 grad "park" is per-wave-constant-tile, so it
// lives in two persistent f32x4 registers instead of 16 KB LDS.
// __launch_bounds__(512,4): 4 waves/EU -> VGPR cap 128 -> 2 blocks/CU.
__global__ __launch_bounds__(512, 4) void icnn_kernel(
    const float* __restrict__ state,
    const float* __restrict__ bz0, const float* __restrict__ bx0,
    const float* __restrict__ bx1, const float* __restrict__ bx2,
    const float* __restrict__ WzL, const float* __restrict__ WxL,
    u16* __restrict__ wsw, float* __restrict__ out) {
  __shared__ u16 zbuf[BM * H];      // XOR-swizzled activations, 64 KB
  __shared__ u16 xbuf[BM * 72];     // padded x staging, 9 KB

  const int tid = threadIdx.x;
  const int w = tid >> 6;           // 0..7
  const int lane = tid & 63;
  const int l15 = lane & 15;
  const int q = lane >> 4;
  const int blk = blockIdx.x;

  const u16* Wz0b = wsw + OFF_Wz0b;
  const u16* Wx0b = wsw + OFF_Wx0b;
  const u16* Wx1b = wsw + OFF_Wx1b;
  const u16* Wx2b = wsw + OFF_Wx2b;
  const u16* Wz1b = wsw + OFF_Wz1b;
  const u16* Wz2b = wsw + OFF_Wz2b;
  const u16* Wz3b = wsw + OFF_Wz3b;
  const u16* Wz1t = wsw + OFF_Wz1t;
  const u16* Wz2t = wsw + OFF_Wz2t;
  const u16* Wz3t = wsw + OFF_Wz3t;
  const u16* Wz0t = wsw + OFF_Wz0t;
  const u16* Wx0t = wsw + OFF_Wx0t;
  const u16* Wx1t = wsw + OFF_Wx1t;
  const u16* Wx2t = wsw + OFF_Wx2t;
  u64* slab0 = (u64*)(wsw + OFF_S0);
  u64* slab1 = (u64*)(wsw + OFF_S1);
  u64* slab2 = (u64*)(wsw + OFF_S2);

  // ---- stage x = state-1 into xbuf (bf16, padded row-major) ----
  {
    int r = tid >> 3, c0 = (tid & 7) << 3;   // 64 rows x 8 chunks of 8 floats
    const float* p = state + (blk * BM + r) * D + c0;
    f32x4 v0 = __builtin_nontemporal_load((const f32x4*)p);
    f32x4 v1 = __builtin_nontemporal_load((const f32x4*)(p + 4));
    u32* dst = (u32*)&xbuf[r * 72 + c0];
    dst[0] = f2b(v0[0] - 1.0f) | (f2b(v0[1] - 1.0f) << 16);
    dst[1] = f2b(v0[2] - 1.0f) | (f2b(v0[3] - 1.0f) << 16);
    dst[2] = f2b(v1[0] - 1.0f) | (f2b(v1[1] - 1.0f) << 16);
    dst[3] = f2b(v1[2] - 1.0f) | (f2b(v1[3] - 1.0f) << 16);
  }

  f32x4 acc[4][4];
  const f32x4 Z = {0.f, 0.f, 0.f, 0.f};
  f32x4 p0 = Z, p1 = Z;   // persistent grad partials (was the 16 KB LDS park)

  auto ldA = [&](int mt, int step) -> bf16x8 {     // LDS A-frag (swizzled)
    int m = mt * 16 + l15;
    int idx = m * H + (((step * 4 + q) ^ (m & 7)) << 3);
    return *(const bf16x8*)(&zbuf[idx]);
  };
  auto ldX = [&](int mt, int ks) -> bf16x8 {       // x A-frag from padded xbuf
    return *(const bf16x8*)(&xbuf[(mt * 16 + l15) * 72 + ks * 32 + q * 8]);
  };
  auto wrZ = [&](int row, int n, u16 bits) {       // swizzled LDS bf16 write
    zbuf[row * H + ((((n >> 3) ^ (row & 7))) << 3) + (n & 7)] = bits;
  };

  // acc (+)= x @ Wx^T (K=64). zero_first: overwrite acc on ks==0.
  auto fwdX = [&](const u16* Wxp, bool zero_first) {
    const u16* xb = Wxp + lane * 8;
#pragma unroll
    for (int ks = 0; ks < 2; ++ks) {
      bf16x8 ax[4];
#pragma unroll
      for (int mt = 0; mt < 4; ++mt) ax[mt] = ldX(mt, ks);
      bf16x8 b4[4];
#pragma unroll
      for (int nt = 0; nt < 4; ++nt)
        b4[nt] = *(const bf16x8*)(xb + ((w * 4 + nt) * 2 + ks) * 512);
#pragma unroll
      for (int nt = 0; nt < 4; ++nt)
#pragma unroll
        for (int mt = 0; mt < 4; ++mt) {
          f32x4 c = (zero_first && ks == 0) ? Z : acc[mt][nt];
          acc[mt][nt] = __builtin_amdgcn_mfma_f32_16x16x32_bf16(ax[mt], b4[nt], c, 0, 0, 0);
        }
    }
  };

  // acc = zbuf @ W^T (K=512), zero-start. Weights stream global->VGPR; the
  // fully unrolled loop lets the scheduler hoist next-step loads under MFMAs.
  auto fwdH = [&](const u16* Wp) {
    const u16* wb = Wp + (w * 4 * 16) * 512 + lane * 8;  // wave's col strip
#pragma unroll
    for (int st = 0; st < 16; ++st) {
      bf16x8 a[4];
#pragma unroll
      for (int mt = 0; mt < 4; ++mt) a[mt] = ldA(mt, st);
#pragma unroll
      for (int nt = 0; nt < 4; ++nt) {
        bf16x8 b = *(const bf16x8*)(wb + (nt * 16 + st) * 512);
#pragma unroll
        for (int mt = 0; mt < 4; ++mt)
          acc[mt][nt] = __builtin_amdgcn_mfma_f32_16x16x32_bf16(
              a[mt], b, (st == 0) ? Z : acc[mt][nt], 0, 0, 0);
      }
    }
  };

  // forward epilogue: a+=bias; z=softplus -> zbuf; s=sigmoid -> slab
  auto fwd_epi = [&](const float* biasp, u64* slab) {
    float bias[4];
#pragma unroll
    for (int nt = 0; nt < 4; ++nt) bias[nt] = biasp[(w * 4 + nt) * 16 + l15];
#pragma unroll
    for (int mt = 0; mt < 4; ++mt)
#pragma unroll
      for (int nt = 0; nt < 4; ++nt) {
        int n = (w * 4 + nt) * 16 + l15;
        f32x4 A = acc[mt][nt];
        u64 pack = 0;
#pragma unroll
        for (int r = 0; r < 4; ++r) {
          float a = A[r] + bias[nt];
          float t = __expf(-a);
          float u = 1.0f + t;
          float s = __builtin_amdgcn_rcpf(u);     // sigmoid(a)
          float z = a + __logf(u);                // softplus(a)
          pack |= (u64)f2b(s) << (16 * r);
          wrZ(mt * 16 + q * 4 + r, n, (u16)f2b(z));
        }
        __builtin_nontemporal_store(
            pack, &slab[((blk * 8 + w) * 16 + mt * 4 + nt) * 64 + lane]);
      }
  };
  auto d3_epi = [&](const float* biasp) {   // d3 = WzL * sigmoid(a3) -> zbuf
    float bias[4], wl[4];
#pragma unroll
    for (int nt = 0; nt < 4; ++nt) {
      bias[nt] = biasp[(w * 4 + nt) * 16 + l15];
      wl[nt] = WzL[(w * 4 + nt) * 16 + l15];
    }
#pragma unroll
    for (int mt = 0; mt < 4; ++mt)
#pragma unroll
      for (int nt = 0; nt < 4; ++nt) {
        int n = (w * 4 + nt) * 16 + l15;
        f32x4 A = acc[mt][nt];
#pragma unroll
        for (int r = 0; r < 4; ++r) {
          float a = A[r] + bias[nt];
          float t = __expf(-a);
          float s = __builtin_amdgcn_rcpf(1.0f + t);
          wrZ(mt * 16 + q * 4 + r, n, (u16)f2b(wl[nt] * s));
        }
      }
  };
  // d = g * s -> zbuf (slab read once; d never re-materialized to global)
  auto bwd_epi = [&](const u64* slab) {
    u64 v[4][4];
#pragma unroll
    for (int mt = 0; mt < 4; ++mt)
#pragma unroll
      for (int nt = 0; nt < 4; ++nt)
        v[mt][nt] = __builtin_nontemporal_load(
            &slab[((blk * 8 + w) * 16 + mt * 4 + nt) * 64 + lane]);
#pragma unroll
    for (int mt = 0; mt < 4; ++mt)
#pragma unroll
      for (int nt = 0; nt < 4; ++nt) {
        int n = (w * 4 + nt) * 16 + l15;
        f32x4 A = acc[mt][nt];
#pragma unroll
        for (int r = 0; r < 4; ++r) {
          float s = b2f((u32)(v[mt][nt] >> (16 * r)) & 0xffffu);
          wrZ(mt * 16 + q * 4 + r, n, (u16)f2b(A[r] * s));
        }
      }
  };

  // grad mini-phase: p += zbuf(d) @ Wg (acc is DEAD here).
  // Wave w owns tiles t0=w, t1=w+8: mt = w&3, cols c0=w>>2, c0+2.
  auto minigrad = [&](const u16* Wg) {
    int mt = w & 3, c0 = w >> 2;
    const u16* gb = Wg + lane * 8;
    f32x4 t0 = p0, t1 = p1;
#pragma unroll
    for (int st = 0; st < 16; ++st) {
      bf16x8 a = ldA(mt, st);
      bf16x8 g0 = *(const bf16x8*)(gb + (c0 * 16 + st) * 512);
      bf16x8 g1 = *(const bf16x8*)(gb + ((c0 + 2) * 16 + st) * 512);
      t0 = __builtin_amdgcn_mfma_f32_16x16x32_bf16(a, g0, t0, 0, 0, 0);
      t1 = __builtin_amdgcn_mfma_f32_16x16x32_bf16(a, g1, t1, 0, 0, 0);
    }
    p0 = t0; p1 = t1;
  };

  // ---------------- forward ----------------
  __syncthreads();                          // xbuf ready
  fwdX(Wz0b, true);                         // a0 = x@Wz0^T
  fwd_epi(bz0, slab0);
  __syncthreads();
  fwdH(Wz1b); fwdX(Wx0b, false);            // a1 = z0@Wz1^T + x@Wx0^T
  __syncthreads();
  fwd_epi(bx0, slab1);
  __syncthreads();
  fwdH(Wz2b); fwdX(Wx1b, false);
  __syncthreads();
  fwd_epi(bx1, slab2);
  __syncthreads();
  fwdH(Wz3b); fwdX(Wx2b, false);            // a3 (last use of xbuf)
  __syncthreads();
  d3_epi(bx2);                              // d3 -> zbuf
  __syncthreads();
  // ---------------- backward ----------------
  minigrad(Wx2t);                           // p  = d3@Wx2t
  fwdH(Wz3t);                               // acc = d3@Wz3
  __syncthreads();
  bwd_epi(slab2);                           // d2 -> zbuf
  __syncthreads();
  minigrad(Wx1t);                           // p += d2@Wx1t
  fwdH(Wz2t);                               // acc = d2@Wz2
  __syncthreads();
  bwd_epi(slab1);                           // d1 -> zbuf
  __syncthreads();
  minigrad(Wx0t);                           // p += d1@Wx0t
  fwdH(Wz1t);                               // acc = d1@Wz1
  __syncthreads();
  bwd_epi(slab0);                           // d0 -> zbuf
  __syncthreads();
  // ---- final: out = d0@Wz0t + p + WxL ----
  minigrad(Wz0t);                           // p += d0@Wz0t
  {
    int mt = w & 3, c0 = w >> 2;
    float wx0 = WxL[c0 * 16 + l15];
    float wx1 = WxL[(c0 + 2) * 16 + l15];
#pragma unroll
    for (int r = 0; r < 4; ++r) {
      int row = blk * BM + mt * 16 + q * 4 + r;
      __builtin_nontemporal_store(p0[r] + wx0, &out[row * D + c0 * 16 + l15]);
      __builtin_nontemporal_store(p1[r] + wx1, &out[row * D + (c0 + 2) * 16 + l15]);
    }
  }
}

extern "C" void kernel_launch(void* const* d_in, const int* in_sizes, int n_in,
                              void* d_out, int out_size, void* d_ws, size_t ws_size,
                              hipStream_t stream) {
  const float* state = (const float*)d_in[0];
  const float* Wz0 = (const float*)d_in[1];
  const float* bz0 = (const float*)d_in[2];
  const float* Wz1 = (const float*)d_in[3];
  const float* Wz2 = (const float*)d_in[4];
  const float* Wz3 = (const float*)d_in[5];
  const float* WzL = (const float*)d_in[6];
  const float* Wx0 = (const float*)d_in[7];
  const float* bx0 = (const float*)d_in[8];
  const float* Wx1 = (const float*)d_in[9];
  const float* bx1 = (const float*)d_in[10];
  const float* Wx2 = (const float*)d_in[11];
  const float* bx2 = (const float*)d_in[12];
  const float* WxL = (const float*)d_in[13];

  if (ws_size < (size_t)WS_ELEMS * 2) {
    fill_sentinel<<<(out_size + 255) / 256, 256, 0, stream>>>((float*)d_out, out_size);
    return;
  }
  u16* wsw = (u16*)d_ws;
  prep_kernel<<<OFF_WEND / 256, 256, 0, stream>>>(Wz0, Wz1, Wz2, Wz3, Wx0, Wx1, Wx2, wsw);
  icnn_kernel<<<B_TOTAL / BM, 512, 0, stream>>>(state, bz0, bx0, bx1, bx2, WzL, WxL,
                                                wsw, (float*)d_out);
}

// Round 2
// 679.817 us; speedup vs baseline: 1.5009x; 1.5009x over previous
//
#include <hip/hip_runtime.h>

typedef unsigned short u16;
typedef unsigned int u32;
typedef unsigned long long u64;

#define B_TOTAL 65536
#define H 512
#define D 64
#define BM 64

typedef __bf16 bf16x8 __attribute__((ext_vector_type(8)));
typedef float f32x4 __attribute__((ext_vector_type(4)));

__device__ __forceinline__ u32 f2b(float f) {  // fp32 -> bf16 bits, RNE
  u32 u = __builtin_bit_cast(u32, f);
  return (u + 0x7fffu + ((u >> 16) & 1u)) >> 16;
}
__device__ __forceinline__ float b2f(u32 bits) {
  return __builtin_bit_cast(float, bits << 16);
}

// ---- workspace layout (bf16 element offsets) ----
// Weight regions are FRAGMENT-PACKED: for logical B-matrix M[NN][KK],
// packed[( (n>>4)*(KK/32) + (k>>5) )*512 + lane*8 + j] = M[n][k],
// n = ntile*16 + (lane&15), k = kstep*32 + (lane>>4)*8 + j.
#define OFF_Wz0b 0          /* [N=512][K=64]  fwd L0 */
#define OFF_Wx0b 32768
#define OFF_Wx1b 65536
#define OFF_Wx2b 98304
#define OFF_Wz1b 131072     /* [N=512][K=512] fwd */
#define OFF_Wz2b 393216
#define OFF_Wz3b 655360
#define OFF_Wz1t 917504     /* [N=512][K=512] transposed, bwd */
#define OFF_Wz2t 1179648
#define OFF_Wz3t 1441792
#define OFF_Wz0t 1703936    /* [N=64][K=512] transposed grad weights */
#define OFF_Wx0t 1736704
#define OFF_Wx1t 1769472
#define OFF_Wx2t 1802240
#define OFF_WEND 1835008
#define SLAB_ELEMS (B_TOTAL * H)          /* 33,554,432 bf16 per slab */
#define OFF_S0 OFF_WEND
#define OFF_S1 (OFF_S0 + SLAB_ELEMS)
#define OFF_S2 (OFF_S1 + SLAB_ELEMS)
#define WS_ELEMS (OFF_S2 + SLAB_ELEMS)    /* ~102.5M elems = ~205 MB */

// ---- weight prep: fp32 -> bf16, fragment-packed (+ transposed variants) ----
__global__ __launch_bounds__(256) void prep_kernel(
    const float* __restrict__ Wz0, const float* __restrict__ Wz1,
    const float* __restrict__ Wz2, const float* __restrict__ Wz3,
    const float* __restrict__ Wx0, const float* __restrict__ Wx1,
    const float* __restrict__ Wx2, u16* __restrict__ wsb) {
  int i = blockIdx.x * 256 + threadIdx.x;   // grid exactly covers OFF_WEND
  const float* src;
  int NN, KK, trans, p;
  if (i < 131072) {                          // x-path fwd: [512][64] direct
    int r = i >> 15; p = i & 32767;
    src = (r == 0) ? Wz0 : (r == 1) ? Wx0 : (r == 2) ? Wx1 : Wx2;
    NN = 512; KK = 64; trans = 0;
  } else if (i < 917504) {                   // H fwd: [512][512] direct
    int j = i - 131072; int r = j >> 18; p = j & 262143;
    src = (r == 0) ? Wz1 : (r == 1) ? Wz2 : Wz3;
    NN = 512; KK = 512; trans = 0;
  } else if (i < 1703936) {                  // H bwd: transposed
    int j = i - 917504; int r = j >> 18; p = j & 262143;
    src = (r == 0) ? Wz1 : (r == 1) ? Wz2 : Wz3;
    NN = 512; KK = 512; trans = 1;
  } else {                                   // grad weights: [64][512] = W^T
    int j = i - 1703936; int r = j >> 15; p = j & 32767;
    src = (r == 0) ? Wz0 : (r == 1) ? Wx0 : (r == 2) ? Wx1 : Wx2;
    NN = 64; KK = 512; trans = 1;
  }
  int jj = p & 7, lane = (p >> 3) & 63, blk = p >> 9;
  int kt_sh = (KK == 64) ? 1 : 4;            // log2(KK/32)
  int ntile = blk >> kt_sh;
  int kstep = blk & ((1 << kt_sh) - 1);
  int n = ntile * 16 + (lane & 15);
  int k = kstep * 32 + ((lane >> 4) << 3) + jj;
  float v = trans ? src[k * NN + n] : src[n * KK + k];
  wsb[i] = (u16)f2b(v);
}

__global__ __launch_bounds__(256) void fill_sentinel(float* out, int n) {
  int i = blockIdx.x * 256 + threadIdx.x;
  if (i < n) out[i] = 12345.0f;   // unmistakable "workspace too small" marker
}

// ---- fully-fused ICNN fwd+bwd (single GEMM kernel) ----
// 512 thr = 8 waves, BM=64 rows; wave w owns cols [w*64,+64) of the [64,512]
// GEMMs (acc[4][4] = 64 acc regs).
// Occupancy: LDS 73 KB + <=128 unified regs/wave -> TWO blocks/CU (16 waves).
// REGISTER DISCIPLINE (round-1 post-mortem): launch_bounds(512,4) leaves only
// 64 arch VGPRs beside the 64 acc regs. Full unrolling of weight-streaming
// loops let LLVM hoist 16 weight frags (64+ VGPRs) -> massive scratch spills
// (+1 GB HBM traffic). Hot loops are now `#pragma unroll 1/2` so the steady
// live set is a[4]+b[4]+acc = ~100 regs; latency hiding comes from 4 waves/EU
// TLP instead of single-wave ILP.
__global__ __launch_bounds__(512, 4) void icnn_kernel(
    const float* __restrict__ state,
    const float* __restrict__ bz0, const float* __restrict__ bx0,
    const float* __restrict__ bx1, const float* __restrict__ bx2,
    const float* __restrict__ WzL, const float* __restrict__ WxL,
    u16* __restrict__ wsw, float* __restrict__ out) {
  __shared__ u16 zbuf[BM * H];      // XOR-swizzled activations, 64 KB
  __shared__ u16 xbuf[BM * 72];     // padded x staging, 9 KB

  const int tid = threadIdx.x;
  const int w = tid >> 6;           // 0..7
  const int lane = tid & 63;
  const int l15 = lane & 15;
  const int q = lane >> 4;
  const int blk = blockIdx.x;

  const u16* Wz0b = wsw + OFF_Wz0b;
  const u16* Wx0b = wsw + OFF_Wx0b;
  const u16* Wx1b = wsw + OFF_Wx1b;
  const u16* Wx2b = wsw + OFF_Wx2b;
  const u16* Wz1b = wsw + OFF_Wz1b;
  const u16* Wz2b = wsw + OFF_Wz2b;
  const u16* Wz3b = wsw + OFF_Wz3b;
  const u16* Wz1t = wsw + OFF_Wz1t;
  const u16* Wz2t = wsw + OFF_Wz2t;
  const u16* Wz3t = wsw + OFF_Wz3t;
  const u16* Wz0t = wsw + OFF_Wz0t;
  const u16* Wx0t = wsw + OFF_Wx0t;
  const u16* Wx1t = wsw + OFF_Wx1t;
  const u16* Wx2t = wsw + OFF_Wx2t;
  u64* slab0 = (u64*)(wsw + OFF_S0);
  u64* slab1 = (u64*)(wsw + OFF_S1);
  u64* slab2 = (u64*)(wsw + OFF_S2);

  // ---- stage x = state-1 into xbuf (bf16, padded row-major) ----
  {
    int r = tid >> 3, c0 = (tid & 7) << 3;   // 64 rows x 8 chunks of 8 floats
    const float* p = state + (blk * BM + r) * D + c0;
    f32x4 v0 = __builtin_nontemporal_load((const f32x4*)p);
    f32x4 v1 = __builtin_nontemporal_load((const f32x4*)(p + 4));
    u32* dst = (u32*)&xbuf[r * 72 + c0];
    dst[0] = f2b(v0[0] - 1.0f) | (f2b(v0[1] - 1.0f) << 16);
    dst[1] = f2b(v0[2] - 1.0f) | (f2b(v0[3] - 1.0f) << 16);
    dst[2] = f2b(v1[0] - 1.0f) | (f2b(v1[1] - 1.0f) << 16);
    dst[3] = f2b(v1[2] - 1.0f) | (f2b(v1[3] - 1.0f) << 16);
  }

  f32x4 acc[4][4];
  const f32x4 Z = {0.f, 0.f, 0.f, 0.f};
  f32x4 p0 = Z, p1 = Z;   // persistent grad partials (register "park")

  auto ldA = [&](int mt, int step) -> bf16x8 {     // LDS A-frag (swizzled)
    int m = mt * 16 + l15;
    int idx = m * H + (((step * 4 + q) ^ (m & 7)) << 3);
    return *(const bf16x8*)(&zbuf[idx]);
  };
  auto ldX = [&](int mt, int ks) -> bf16x8 {       // x A-frag from padded xbuf
    return *(const bf16x8*)(&xbuf[(mt * 16 + l15) * 72 + ks * 32 + q * 8]);
  };
  auto wrZ = [&](int row, int n, u16 bits) {       // swizzled LDS bf16 write
    zbuf[row * H + ((((n >> 3) ^ (row & 7))) << 3) + (n & 7)] = bits;
  };
  auto zeroAcc = [&]() {
#pragma unroll
    for (int mt = 0; mt < 4; ++mt)
#pragma unroll
      for (int nt = 0; nt < 4; ++nt) acc[mt][nt] = Z;
  };

  // acc += x @ Wx^T (K=64). unroll 1: cap live weight frags.
  auto fwdX = [&](const u16* Wxp) {
    const u16* xb = Wxp + lane * 8;
#pragma unroll 1
    for (int ks = 0; ks < 2; ++ks) {
      bf16x8 ax[4];
#pragma unroll
      for (int mt = 0; mt < 4; ++mt) ax[mt] = ldX(mt, ks);
      bf16x8 b4[4];
#pragma unroll
      for (int nt = 0; nt < 4; ++nt)
        b4[nt] = *(const bf16x8*)(xb + ((w * 4 + nt) * 2 + ks) * 512);
#pragma unroll
      for (int nt = 0; nt < 4; ++nt)
#pragma unroll
        for (int mt = 0; mt < 4; ++mt)
          acc[mt][nt] = __builtin_amdgcn_mfma_f32_16x16x32_bf16(ax[mt], b4[nt],
                                                                acc[mt][nt], 0, 0, 0);
    }
  };

  // acc += zbuf @ W^T (K=512). Weights stream global->VGPR; unroll 1 keeps
  // the live set to a[4]+b[4] (32 regs) beside acc; 4 waves/EU hide latency.
  auto fwdH = [&](const u16* Wp) {
    const u16* wb = Wp + (w * 4 * 16) * 512 + lane * 8;  // wave's col strip
#pragma unroll 1
    for (int st = 0; st < 16; ++st) {
      bf16x8 a[4];
#pragma unroll
      for (int mt = 0; mt < 4; ++mt) a[mt] = ldA(mt, st);
      bf16x8 b[4];
#pragma unroll
      for (int nt = 0; nt < 4; ++nt)
        b[nt] = *(const bf16x8*)(wb + (nt * 16 + st) * 512);
#pragma unroll
      for (int nt = 0; nt < 4; ++nt)
#pragma unroll
        for (int mt = 0; mt < 4; ++mt)
          acc[mt][nt] = __builtin_amdgcn_mfma_f32_16x16x32_bf16(a[mt], b[nt],
                                                                acc[mt][nt], 0, 0, 0);
    }
  };

  // forward epilogue: a+=bias; z=softplus -> zbuf; s=sigmoid -> slab
  auto fwd_epi = [&](const float* biasp, u64* slab) {
    float bias[4];
#pragma unroll
    for (int nt = 0; nt < 4; ++nt) bias[nt] = biasp[(w * 4 + nt) * 16 + l15];
#pragma unroll 1
    for (int mt = 0; mt < 4; ++mt)
#pragma unroll
      for (int nt = 0; nt < 4; ++nt) {
        int n = (w * 4 + nt) * 16 + l15;
        f32x4 A = acc[mt][nt];
        u64 pack = 0;
#pragma unroll
        for (int r = 0; r < 4; ++r) {
          float a = A[r] + bias[nt];
          float t = __expf(-a);
          float u = 1.0f + t;
          float s = __builtin_amdgcn_rcpf(u);     // sigmoid(a)
          float z = a + __logf(u);                // softplus(a)
          pack |= (u64)f2b(s) << (16 * r);
          wrZ(mt * 16 + q * 4 + r, n, (u16)f2b(z));
        }
        slab[((blk * 8 + w) * 16 + mt * 4 + nt) * 64 + lane] = pack;
      }
  };
  auto d3_epi = [&](const float* biasp) {   // d3 = WzL * sigmoid(a3) -> zbuf
    float bias[4], wl[4];
#pragma unroll
    for (int nt = 0; nt < 4; ++nt) {
      bias[nt] = biasp[(w * 4 + nt) * 16 + l15];
      wl[nt] = WzL[(w * 4 + nt) * 16 + l15];
    }
#pragma unroll 1
    for (int mt = 0; mt < 4; ++mt)
#pragma unroll
      for (int nt = 0; nt < 4; ++nt) {
        int n = (w * 4 + nt) * 16 + l15;
        f32x4 A = acc[mt][nt];
#pragma unroll
        for (int r = 0; r < 4; ++r) {
          float a = A[r] + bias[nt];
          float t = __expf(-a);
          float s = __builtin_amdgcn_rcpf(1.0f + t);
          wrZ(mt * 16 + q * 4 + r, n, (u16)f2b(wl[nt] * s));
        }
      }
  };
  // d = g * s -> zbuf (slab read once; d never re-materialized to global)
  auto bwd_epi = [&](const u64* slab) {
#pragma unroll 1
    for (int mt = 0; mt < 4; ++mt) {
      u64 v[4];
#pragma unroll
      for (int nt = 0; nt < 4; ++nt)
        v[nt] = slab[((blk * 8 + w) * 16 + mt * 4 + nt) * 64 + lane];
#pragma unroll
      for (int nt = 0; nt < 4; ++nt) {
        int n = (w * 4 + nt) * 16 + l15;
        f32x4 A = acc[mt][nt];
#pragma unroll
        for (int r = 0; r < 4; ++r) {
          float s = b2f((u32)(v[nt] >> (16 * r)) & 0xffffu);
          wrZ(mt * 16 + q * 4 + r, n, (u16)f2b(A[r] * s));
        }
      }
    }
  };

  // grad mini-phase: p += zbuf(d) @ Wg (acc is DEAD here).
  // Wave w owns tiles t0=w, t1=w+8: mt = w&3, cols c0=w>>2, c0+2.
  // unroll 2: two dependent MFMA chains x2 for ILP, live set stays ~40 regs.
  auto minigrad = [&](const u16* Wg) {
    int mt = w & 3, c0 = w >> 2;
    const u16* gb = Wg + lane * 8;
    f32x4 t0 = p0, t1 = p1;
#pragma unroll 2
    for (int st = 0; st < 16; ++st) {
      bf16x8 a = ldA(mt, st);
      bf16x8 g0 = *(const bf16x8*)(gb + (c0 * 16 + st) * 512);
      bf16x8 g1 = *(const bf16x8*)(gb + ((c0 + 2) * 16 + st) * 512);
      t0 = __builtin_amdgcn_mfma_f32_16x16x32_bf16(a, g0, t0, 0, 0, 0);
      t1 = __builtin_amdgcn_mfma_f32_16x16x32_bf16(a, g1, t1, 0, 0, 0);
    }
    p0 = t0; p1 = t1;
  };

  // ---------------- forward ----------------
  // Per layer: [epi writes zbuf] [fwdX: xbuf-only MFMA, overlaps others' epi]
  // [sync A: z ready] [fwdH reads zbuf] [sync B: reads done before next epi].
  __syncthreads();                          // xbuf ready
  zeroAcc(); fwdX(Wz0b);                    // a0 = x@Wz0^T
  fwd_epi(bz0, slab0);                      // z0 -> zbuf
  zeroAcc(); fwdX(Wx0b);                    // acc = x@Wx0^T (xbuf only)
  __syncthreads();                          // A: z0 visible
  fwdH(Wz1b);                               // acc += z0@Wz1^T
  __syncthreads();                          // B: all reads of z0 done
  fwd_epi(bx0, slab1);                      // z1 -> zbuf
  zeroAcc(); fwdX(Wx1b);
  __syncthreads();                          // A
  fwdH(Wz2b);
  __syncthreads();                          // B
  fwd_epi(bx1, slab2);                      // z2 -> zbuf
  zeroAcc(); fwdX(Wx2b);                    // (last use of xbuf)
  __syncthreads();                          // A
  fwdH(Wz3b);                               // a3
  __syncthreads();                          // B
  d3_epi(bx2);                              // d3 -> zbuf
  __syncthreads();                          // A
  // ---------------- backward ----------------
  minigrad(Wx2t);                           // p  = d3@Wx2t
  zeroAcc(); fwdH(Wz3t);                    // acc = d3@Wz3
  __syncthreads();                          // B
  bwd_epi(slab2);                           // d2 -> zbuf
  __syncthreads();                          // A
  minigrad(Wx1t);                           // p += d2@Wx1t
  zeroAcc(); fwdH(Wz2t);                    // acc = d2@Wz2
  __syncthreads();                          // B
  bwd_epi(slab1);                           // d1 -> zbuf
  __syncthreads();                          // A
  minigrad(Wx0t);                           // p += d1@Wx0t
  zeroAcc(); fwdH(Wz1t);                    // acc = d1@Wz1
  __syncthreads();                          // B
  bwd_epi(slab0);                           // d0 -> zbuf
  __syncthreads();                          // A
  // ---- final: out = d0@Wz0t + p + WxL ----
  minigrad(Wz0t);                           // p += d0@Wz0t
  {
    int mt = w & 3, c0 = w >> 2;
    float wx0 = WxL[c0 * 16 + l15];
    float wx1 = WxL[(c0 + 2) * 16 + l15];
#pragma unroll
    for (int r = 0; r < 4; ++r) {
      int row = blk * BM + mt * 16 + q * 4 + r;
      out[row * D + c0 * 16 + l15] = p0[r] + wx0;
      out[row * D + (c0 + 2) * 16 + l15] = p1[r] + wx1;
    }
  }
}

extern "C" void kernel_launch(void* const* d_in, const int* in_sizes, int n_in,
                              void* d_out, int out_size, void* d_ws, size_t ws_size,
                              hipStream_t stream) {
  const float* state = (const float*)d_in[0];
  const float* Wz0 = (const float*)d_in[1];
  const float* bz0 = (const float*)d_in[2];
  const float* Wz1 = (const float*)d_in[3];
  const float* Wz2 = (const float*)d_in[4];
  const float* Wz3 = (const float*)d_in[5];
  const float* WzL = (const float*)d_in[6];
  const float* Wx0 = (const float*)d_in[7];
  const float* bx0 = (const float*)d_in[8];
  const float* Wx1 = (const float*)d_in[9];
  const float* bx1 = (const float*)d_in[10];
  const float* Wx2 = (const float*)d_in[11];
  const float* bx2 = (const float*)d_in[12];
  const float* WxL = (const float*)d_in[13];

  if (ws_size < (size_t)WS_ELEMS * 2) {
    fill_sentinel<<<(out_size + 255) / 256, 256, 0, stream>>>((float*)d_out, out_size);
    return;
  }
  u16* wsw = (u16*)d_ws;
  prep_kernel<<<OFF_WEND / 256, 256, 0, stream>>>(Wz0, Wz1, Wz2, Wz3, Wx0, Wx1, Wx2, wsw);
  icnn_kernel<<<B_TOTAL / BM, 512, 0, stream>>>(state, bz0, bx0, bx1, bx2, WzL, WxL,
                                                wsw, (float*)d_out);
}